// Round 6
// baseline (1751.027 us; speedup 1.0000x reference)
//
#include <hip/hip_runtime.h>

typedef _Float16 f16;
typedef _Float16 f16x8 __attribute__((ext_vector_type(8)));
typedef float    f32x4 __attribute__((ext_vector_type(4)));

#define MFMA16(a,b,c) __builtin_amdgcn_mfma_f32_16x16x32_f16(a,b,c,0,0,0)

#define HB_S   136            // per-sample stride within one t-slot (128+8), 272 B (16B aligned)
#define H4S    552            // hist4 per-sample row stride: 4*HB_S + 8 -> 1104 B (16B aligned)
#define RB     (64*HB_S)      // one ring buffer: 64 samples
#define ZS     72             // zbuf per-sample stride (64+8) -> 144 B (16B aligned)

__device__ __forceinline__ float sigm(float v){
  return __builtin_amdgcn_rcpf(1.f + __builtin_amdgcn_exp2f(-1.4426950408889634f*v));
}
__device__ __forceinline__ float tanha(float v){
  return 1.f - 2.f*__builtin_amdgcn_rcpf(1.f + __builtin_amdgcn_exp2f(2.8853900817779268f*v));
}
__device__ __forceinline__ f32x4 splat4(float v){ f32x4 r; r[0]=v;r[1]=v;r[2]=v;r[3]=v; return r; }

// 8 consecutive f32 from row-major W[n][k] at (n,k0) -> f16 B-fragment
__device__ __forceinline__ f16x8 ldfrag(const float* __restrict__ W, int K, int n, int k0){
  const float* p = W + n*K + k0;
  f32x4 a = *(const f32x4*)p;
  f32x4 b = *(const f32x4*)(p+4);
  f16x8 r;
  #pragma unroll
  for (int i=0;i<4;i++){ r[i] = (f16)a[i]; r[4+i] = (f16)b[i]; }
  return r;
}
// K=60 rows, zero-pad k>=60 (only k0==56 crosses the edge)
__device__ __forceinline__ f16x8 ldfrag60(const float* __restrict__ W, int n, int k0){
  const float* p = W + n*60 + k0;
  f32x4 a = *(const f32x4*)p;
  f16x8 r;
  #pragma unroll
  for (int i=0;i<4;i++) r[i] = (f16)a[i];
  if (k0 < 56){
    f32x4 b = *(const f32x4*)(p+4);
    #pragma unroll
    for (int i=0;i<4;i++) r[4+i] = (f16)b[i];
  } else {
    #pragma unroll
    for (int i=0;i<4;i++) r[4+i] = (f16)0.f;
  }
  return r;
}
__device__ __forceinline__ f16x8 zfrag(){
  f16x8 r;
  #pragma unroll
  for (int i=0;i<8;i++) r[i] = (f16)0.f;
  return r;
}

// gate nonlinearities + c/h update for one m-pair (samples (mbase..mbase+1)*16 block)
__device__ __forceinline__ void act2(f32x4 acc[2][4], f32x4* cst, f16* dst, int stride,
                                     int col, int qd, int mbase){
  #pragma unroll
  for (int m=0;m<2;m++){
    #pragma unroll
    for (int r=0;r<4;r++){
      float ii = sigm(acc[m][0][r]);
      float ff = sigm(acc[m][1][r]);
      float gg = tanha(acc[m][2][r]);
      float oo = sigm(acc[m][3][r]);
      float cn = ff*cst[m][r] + ii*gg;
      cst[m][r] = cn;
      dst[((mbase+m)*16+qd*4+r)*stride + col] = (f16)(oo*tanha(cn));
    }
  }
}

// R0-R5 evidence: phase latency (~6.8k cyc) >> issue work; occupancy and I$ levers
// are dead (register wall / falsified). This version: M=4 (64 samples/block),
// two sub-batches per phase sharing acc[2][4]; per-layer 4-t half-split so the
// history buffer needs only 4 slots (LDS 114,688 B <= proven 128 KB zone);
// xg_dec0 recomputed per t from zbuf (kills the xga register array); ring
// double-buffered -> 1 barrier per timestep (R0 discipline).
__global__ void __launch_bounds__(512, 2)
lstm_main(const float* __restrict__ x,
          const float* __restrict__ e0Wih, const float* __restrict__ e0Whh, const float* __restrict__ e0bi, const float* __restrict__ e0bh,
          const float* __restrict__ e1Wih, const float* __restrict__ e1Whh, const float* __restrict__ e1bi, const float* __restrict__ e1bh,
          const float* __restrict__ d0Wih, const float* __restrict__ d0Whh, const float* __restrict__ d0bi, const float* __restrict__ d0bh,
          const float* __restrict__ d1Wih, const float* __restrict__ d1Whh, const float* __restrict__ d1bi, const float* __restrict__ d1bh,
          const float* __restrict__ Wlat,  const float* __restrict__ blat,
          const float* __restrict__ Wout,  const float* __restrict__ bout,
          float* __restrict__ out)
{
  __shared__ __align__(16) f16 hist4[64*H4S];   // 70656 B: 4-slot h0/d0 history, 64 samples
  __shared__ __align__(16) f16 ring [2*RB];     // 34816 B: double-buffered h1 / h_d1
  __shared__ __align__(16) f16 zbuf [64*ZS];    //  9216 B: latent z
  // total LDS = 114688 B

  const int tid = threadIdx.x;
  const int w   = tid >> 6;        // wave 0..7
  const int ln  = tid & 15;
  const int qd  = (tid >> 4) & 3;
  const int bs  = blockIdx.x << 6; // 64 samples per WG
  const int col = w*16 + ln;       // unit index within gate, 0..127

  f16x8 Bf[4][8];
  f32x4 acc[2][4];
  f32x4 cstA[4], cstB[4];          // cell states: enc0/dec0 and enc1/dec1 (4 m-tiles)
  float bg[4];

  // =================================== ENCODER =============================
  #pragma unroll
  for (int m=0;m<4;m++){ cstA[m] = splat4(0.f); cstB[m] = splat4(0.f); }

  #pragma unroll 1
  for (int half=0; half<2; ++half){
    const int t0 = half*4;
    // ---- session: enc0 weights (Bf[g][0..1]=Wih(K=60pad), [2..5]=Whh) ----
    #pragma unroll
    for (int g=0;g<4;g++){
      const int n = g*128 + col;
      #pragma unroll
      for (int kb=0;kb<2;kb++) Bf[g][kb]   = ldfrag60(e0Wih, n, kb*32 + qd*8);
      #pragma unroll
      for (int kb=0;kb<4;kb++) Bf[g][kb+2] = ldfrag(e0Whh, 128, n, kb*32 + qd*8);
      bg[g] = e0bi[n] + e0bh[n];
    }
    // ---- P1: enc layer 0, t = t0..t0+3 ----
    #pragma unroll 1
    for (int t=t0; t<t0+4; ++t){
      const int slotW = (t&3)*HB_S, slotR = ((t-1)&3)*HB_S;
      #pragma unroll
      for (int mb=0; mb<2; ++mb){
        #pragma unroll
        for (int m=0;m<2;m++)
          #pragma unroll
          for (int g=0;g<4;g++) acc[m][g] = splat4(bg[g]);
        #pragma unroll
        for (int kb=0; kb<2; kb++){          // x part (global f32 -> f16)
          #pragma unroll
          for (int m=0;m<2;m++){
            const float* p = x + (bs + (mb*2+m)*16 + ln)*480 + t*60 + kb*32 + qd*8;
            f16x8 a;
            f32x4 lo = *(const f32x4*)p;
            #pragma unroll
            for (int i=0;i<4;i++) a[i] = (f16)lo[i];
            if (kb==1 && qd==3){
              #pragma unroll
              for (int i=0;i<4;i++) a[4+i] = (f16)0.f;   // k=60..63 pad
            } else {
              f32x4 hi = *(const f32x4*)(p+4);
              #pragma unroll
              for (int i=0;i<4;i++) a[4+i] = (f16)hi[i];
            }
            #pragma unroll
            for (int g=0; g<4; g++) acc[m][g] = MFMA16(a, Bf[g][kb], acc[m][g]);
          }
        }
        if (t > 0){                          // h0_{t-1} from slot (t-1)&3
          #pragma unroll
          for (int kb=0; kb<4; kb++){
            #pragma unroll
            for (int m=0;m<2;m++){
              f16x8 a = *(const f16x8*)(hist4 + ((mb*2+m)*16+ln)*H4S + slotR + kb*32 + qd*8);
              #pragma unroll
              for (int g=0; g<4; g++) acc[m][g] = MFMA16(a, Bf[g][kb+2], acc[m][g]);
            }
          }
        }
        act2(acc, &cstA[mb*2], hist4 + slotW, H4S, col, qd, mb*2);
      }
      __syncthreads();                       // slot t visible (reads were from slot t-1: disjoint)
    }
    // ---- session: enc1 weights (Bf[0..3]=Wih, [4..7]=Whh) ----
    #pragma unroll
    for (int g=0;g<4;g++){
      const int n = g*128 + col;
      #pragma unroll
      for (int kb=0;kb<4;kb++){
        Bf[g][kb]   = ldfrag(e1Wih, 128, n, kb*32 + qd*8);
        Bf[g][kb+4] = ldfrag(e1Whh, 128, n, kb*32 + qd*8);
      }
      bg[g] = e1bi[n] + e1bh[n];
    }
    // ---- P2: enc layer 1, t = t0..t0+3 ----
    #pragma unroll 1
    for (int t=t0; t<t0+4; ++t){
      const int slot = (t&3)*HB_S;
      const f16* rprev = ring + ((t-1)&1)*RB;
      f16*       rcur  = ring + (t&1)*RB;
      #pragma unroll
      for (int mb=0; mb<2; ++mb){
        #pragma unroll
        for (int m=0;m<2;m++)
          #pragma unroll
          for (int g=0;g<4;g++) acc[m][g] = splat4(bg[g]);
        #pragma unroll
        for (int kb=0; kb<4; kb++){          // h0_t
          #pragma unroll
          for (int m=0;m<2;m++){
            f16x8 a = *(const f16x8*)(hist4 + ((mb*2+m)*16+ln)*H4S + slot + kb*32 + qd*8);
            #pragma unroll
            for (int g=0; g<4; g++) acc[m][g] = MFMA16(a, Bf[g][kb], acc[m][g]);
          }
        }
        if (t > 0){                          // h1_{t-1} from other ring buffer
          #pragma unroll
          for (int kb=0; kb<4; kb++){
            #pragma unroll
            for (int m=0;m<2;m++){
              f16x8 a = *(const f16x8*)(rprev + ((mb*2+m)*16+ln)*HB_S + kb*32 + qd*8);
              #pragma unroll
              for (int g=0; g<4; g++) acc[m][g] = MFMA16(a, Bf[g][kb+4], acc[m][g]);
            }
          }
        }
        act2(acc, &cstB[mb*2], rcur, HB_S, col, qd, mb*2);   // writes OTHER buffer than rprev
      }
      __syncthreads();
    }
  }

  // ============== P3: z = h1_7 @ Wlat^T + blat -> zbuf (f16) ===============
  {
    const int mo = w & 3, nb = w >> 2;       // wave: m-tile mo, n-tiles {nb, nb+2}
    const f16* r1 = ring + RB;               // h1_7 lives in ring[1] (7&1)
    f16x8 Az[4];
    #pragma unroll
    for (int kb=0;kb<4;kb++)
      Az[kb] = *(const f16x8*)(r1 + (mo*16+ln)*HB_S + kb*32 + qd*8);
    #pragma unroll
    for (int h2=0; h2<2; ++h2){
      const int zn = (nb + 2*h2)*16 + ln;    // latent index 0..63
      f32x4 zacc = splat4(blat[zn]);
      #pragma unroll
      for (int kb=0;kb<4;kb++){
        f16x8 Bz = ldfrag(Wlat, 128, zn, kb*32 + qd*8);
        zacc = MFMA16(Az[kb], Bz, zacc);
      }
      #pragma unroll
      for (int r=0;r<4;r++)
        zbuf[(mo*16+qd*4+r)*ZS + zn] = (f16)zacc[r];
    }
    __syncthreads();
  }

  // =================================== DECODER =============================
  #pragma unroll
  for (int m=0;m<4;m++){ cstA[m] = splat4(0.f); cstB[m] = splat4(0.f); }

  // out-projection fragments (persist through both halves)
  const int mo   = w & 3;
  const int nb   = w >> 2;
  int  dcolH[2]; float boH[2];
  f16x8 BO[2][4];
  #pragma unroll
  for (int h2=0; h2<2; ++h2){
    dcolH[h2] = (nb + 2*h2)*16 + ln;
    boH[h2]   = (dcolH[h2] < 60) ? bout[dcolH[h2]] : 0.f;
    #pragma unroll
    for (int kb=0;kb<4;kb++)
      BO[h2][kb] = (dcolH[h2] < 60) ? ldfrag(Wout, 128, dcolH[h2], kb*32 + qd*8) : zfrag();
  }

  #pragma unroll 1
  for (int half=0; half<2; ++half){
    const int t0 = half*4;
    // ---- session: dec0 weights (Bf[0..1]=Wih(K=64), [2..5]=Whh) ----
    #pragma unroll
    for (int g=0;g<4;g++){
      const int n = g*128 + col;
      #pragma unroll
      for (int kb=0;kb<2;kb++) Bf[g][kb]   = ldfrag(d0Wih, 64, n, kb*32 + qd*8);
      #pragma unroll
      for (int kb=0;kb<4;kb++) Bf[g][kb+2] = ldfrag(d0Whh, 128, n, kb*32 + qd*8);
      bg[g] = d0bi[n] + d0bh[n];
    }
    // ---- P4: dec layer 0, t = t0..t0+3 (xg recomputed from zbuf each t) ----
    #pragma unroll 1
    for (int t=t0; t<t0+4; ++t){
      const int slotW = (t&3)*HB_S, slotR = ((t-1)&3)*HB_S;
      #pragma unroll
      for (int mb=0; mb<2; ++mb){
        #pragma unroll
        for (int m=0;m<2;m++)
          #pragma unroll
          for (int g=0;g<4;g++) acc[m][g] = splat4(bg[g]);
        #pragma unroll
        for (int kb=0; kb<2; kb++){          // z part (K=64)
          #pragma unroll
          for (int m=0;m<2;m++){
            f16x8 a = *(const f16x8*)(zbuf + ((mb*2+m)*16+ln)*ZS + kb*32 + qd*8);
            #pragma unroll
            for (int g=0; g<4; g++) acc[m][g] = MFMA16(a, Bf[g][kb], acc[m][g]);
          }
        }
        if (t > 0){                          // d0_{t-1}
          #pragma unroll
          for (int kb=0; kb<4; kb++){
            #pragma unroll
            for (int m=0;m<2;m++){
              f16x8 a = *(const f16x8*)(hist4 + ((mb*2+m)*16+ln)*H4S + slotR + kb*32 + qd*8);
              #pragma unroll
              for (int g=0; g<4; g++) acc[m][g] = MFMA16(a, Bf[g][kb+2], acc[m][g]);
            }
          }
        }
        act2(acc, &cstA[mb*2], hist4 + slotW, H4S, col, qd, mb*2);
      }
      __syncthreads();
    }
    // ---- session: dec1 weights ----
    #pragma unroll
    for (int g=0;g<4;g++){
      const int n = g*128 + col;
      #pragma unroll
      for (int kb=0;kb<4;kb++){
        Bf[g][kb]   = ldfrag(d1Wih, 128, n, kb*32 + qd*8);
        Bf[g][kb+4] = ldfrag(d1Whh, 128, n, kb*32 + qd*8);
      }
      bg[g] = d1bi[n] + d1bh[n];
    }
    // ---- P5: dec layer 1 + out-projection, t = t0..t0+3 ----
    #pragma unroll 1
    for (int t=t0; t<t0+4; ++t){
      const int slot = (t&3)*HB_S;
      const f16* rprev = ring + ((t-1)&1)*RB;
      f16*       rcur  = ring + (t&1)*RB;
      #pragma unroll
      for (int mb=0; mb<2; ++mb){
        #pragma unroll
        for (int m=0;m<2;m++)
          #pragma unroll
          for (int g=0;g<4;g++) acc[m][g] = splat4(bg[g]);
        #pragma unroll
        for (int kb=0; kb<4; kb++){          // d0_t
          #pragma unroll
          for (int m=0;m<2;m++){
            f16x8 a = *(const f16x8*)(hist4 + ((mb*2+m)*16+ln)*H4S + slot + kb*32 + qd*8);
            #pragma unroll
            for (int g=0; g<4; g++) acc[m][g] = MFMA16(a, Bf[g][kb], acc[m][g]);
          }
        }
        if (t > 0){                          // h_d1_{t-1}
          #pragma unroll
          for (int kb=0; kb<4; kb++){
            #pragma unroll
            for (int m=0;m<2;m++){
              f16x8 a = *(const f16x8*)(rprev + ((mb*2+m)*16+ln)*HB_S + kb*32 + qd*8);
              #pragma unroll
              for (int g=0; g<4; g++) acc[m][g] = MFMA16(a, Bf[g][kb+4], acc[m][g]);
            }
          }
        }
        act2(acc, &cstB[mb*2], rcur, HB_S, col, qd, mb*2);
      }
      __syncthreads();                       // h_d1_t visible
      // ---- out_t = h_d1_t @ W_out^T + b_out (wave: m-tile mo x n-tiles {nb,nb+2})
      // safe: next write to rcur's buffer is at t+2, after barrier(t+1) which this
      // wave only reaches after finishing here.
      #pragma unroll
      for (int h2=0; h2<2; ++h2){
        f32x4 ao = splat4(boH[h2]);
        #pragma unroll
        for (int kb=0; kb<4; kb++){
          f16x8 a = *(const f16x8*)(rcur + (mo*16+ln)*HB_S + kb*32 + qd*8);
          ao = MFMA16(a, BO[h2][kb], ao);
        }
        if (dcolH[h2] < 60){
          #pragma unroll
          for (int r=0;r<4;r++){
            int s = mo*16 + qd*4 + r;
            out[(bs + s)*480 + t*60 + dcolH[h2]] = ao[r];
          }
        }
      }
    }
  }
}

// ---------------- host launch ---------------------------------------------
extern "C" void kernel_launch(void* const* d_in, const int* in_sizes, int n_in,
                              void* d_out, int out_size, void* d_ws, size_t ws_size,
                              hipStream_t stream)
{
  (void)d_ws; (void)ws_size; (void)in_sizes; (void)n_in; (void)out_size;
  hipLaunchKernelGGL(lstm_main, dim3(1024), dim3(512), 0, stream,
                     (const float*)d_in[0],
                     (const float*)d_in[1],  (const float*)d_in[2],  (const float*)d_in[3],  (const float*)d_in[4],
                     (const float*)d_in[5],  (const float*)d_in[6],  (const float*)d_in[7],  (const float*)d_in[8],
                     (const float*)d_in[9],  (const float*)d_in[10], (const float*)d_in[11], (const float*)d_in[12],
                     (const float*)d_in[13], (const float*)d_in[14], (const float*)d_in[15], (const float*)d_in[16],
                     (const float*)d_in[17], (const float*)d_in[18],
                     (const float*)d_in[19], (const float*)d_in[20],
                     (float*)d_out);
}

// Round 7
// 1370.883 us; speedup vs baseline: 1.2773x; 1.2773x over previous
//
#include <hip/hip_runtime.h>

typedef _Float16 f16;
typedef _Float16 f16x8 __attribute__((ext_vector_type(8)));
typedef float    f32x4 __attribute__((ext_vector_type(4)));

#define MFMA16(a,b,c) __builtin_amdgcn_mfma_f32_16x16x32_f16(a,b,c,0,0,0)

#define HIST_S 1096   // per-sample stride in hist (8*136 + 8 pad), *2B = 2192 (16B aligned, bank-skewed)
#define HB_S   136    // per-sample stride in hb1 (128 + 8 pad), *2B = 272 (16B aligned)
#define HB_BUF 4352   // 32*HB_S; hb1 is DOUBLE-buffered again (R0 discipline, 1 barrier/t)

__device__ __forceinline__ float sigm(float v){
  return __builtin_amdgcn_rcpf(1.f + __builtin_amdgcn_exp2f(-1.4426950408889634f*v));
}
__device__ __forceinline__ float tanha(float v){
  return 1.f - 2.f*__builtin_amdgcn_rcpf(1.f + __builtin_amdgcn_exp2f(2.8853900817779268f*v));
}
__device__ __forceinline__ f32x4 splat4(float v){ f32x4 r; r[0]=v;r[1]=v;r[2]=v;r[3]=v; return r; }

// 8 consecutive f32 from row-major W[n][k] at (n,k0) -> f16 B-fragment
__device__ __forceinline__ f16x8 ldfrag(const float* __restrict__ W, int K, int n, int k0){
  const float* p = W + n*K + k0;
  f32x4 a = *(const f32x4*)p;
  f32x4 b = *(const f32x4*)(p+4);
  f16x8 r;
  #pragma unroll
  for (int i=0;i<4;i++){ r[i] = (f16)a[i]; r[4+i] = (f16)b[i]; }
  return r;
}
// K=60 rows, zero-pad k>=60 (only k0==56 crosses the edge)
__device__ __forceinline__ f16x8 ldfrag60(const float* __restrict__ W, int n, int k0){
  const float* p = W + n*60 + k0;
  f32x4 a = *(const f32x4*)p;
  f16x8 r;
  #pragma unroll
  for (int i=0;i<4;i++) r[i] = (f16)a[i];
  if (k0 < 56){
    f32x4 b = *(const f32x4*)(p+4);
    #pragma unroll
    for (int i=0;i<4;i++) r[4+i] = (f16)b[i];
  } else {
    #pragma unroll
    for (int i=0;i<4;i++) r[4+i] = (f16)0.f;
  }
  return r;
}
__device__ __forceinline__ f16x8 zfrag(){
  f16x8 r;
  #pragma unroll
  for (int i=0;i<8;i++) r[i] = (f16)0.f;
  return r;
}

// gate nonlinearities + c/h update; writes h (f16) to dst[(m*16+qd*4+r)*stride + col]
__device__ __forceinline__ void act_update(f32x4 acc[2][4], f32x4* cst, f16* dst, int stride, int col, int qd){
  #pragma unroll
  for (int m=0;m<2;m++){
    #pragma unroll
    for (int r=0;r<4;r++){
      float ii = sigm(acc[m][0][r]);
      float ff = sigm(acc[m][1][r]);
      float gg = tanha(acc[m][2][r]);
      float oo = sigm(acc[m][3][r]);
      float cn = ff*cst[m][r] + ii*gg;
      cst[m][r] = cn;
      dst[(m*16+qd*4+r)*stride + col] = (f16)(oo*tanha(cn));
    }
  }
}

// R0-R6 ledger: occupancy lever dead (256-reg/wave wall, R1/R4); I$ falsified (R5);
// M=4 spilled (R6). This round: cross-t software pipelining -- each interval t
// also computes accN = bias + Wih*(input of t+1), whose operands are ready one
// interval early; those independent MFMA+ds_reads fill the activation/latency
// shadow. P4 recomputes the (t-invariant) z-part per t as injected work,
// replacing the stored xga (net 0 regs). hb1 double-buffered (1 barrier/t).
__global__ void __launch_bounds__(512, 2)
lstm_main(const float* __restrict__ x,
          const float* __restrict__ e0Wih, const float* __restrict__ e0Whh, const float* __restrict__ e0bi, const float* __restrict__ e0bh,
          const float* __restrict__ e1Wih, const float* __restrict__ e1Whh, const float* __restrict__ e1bi, const float* __restrict__ e1bh,
          const float* __restrict__ d0Wih, const float* __restrict__ d0Whh, const float* __restrict__ d0bi, const float* __restrict__ d0bh,
          const float* __restrict__ d1Wih, const float* __restrict__ d1Whh, const float* __restrict__ d1bi, const float* __restrict__ d1bh,
          const float* __restrict__ Wlat,  const float* __restrict__ blat,
          const float* __restrict__ Wout,  const float* __restrict__ bout,
          float* __restrict__ out)
{
  __shared__ __align__(16) f16 hist[32*HIST_S];  // 70144 B: h0 history (enc), then d0 history (dec)
  __shared__ __align__(16) f16 hb1 [2*HB_BUF];   // 17408 B: double-buffered h1 / h_d1 (+ z in buf0)
  // total LDS = 87552 B (R0's proven config)

  const int tid = threadIdx.x;
  const int w   = tid >> 6;        // wave 0..7
  const int ln  = tid & 15;
  const int qd  = (tid >> 4) & 3;
  const int bs  = blockIdx.x << 5; // 32 samples per WG
  const int col = w*16 + ln;       // unit index within gate, 0..127

  f16x8 Bf[4][8];
  f32x4 acc[2][4], accN[2][4];
  f32x4 cst[2];
  float bg[4];

  // x A-fragment loader (global f32 -> f16), zero-pads k=60..63
  auto xfrag = [&](int m, int t, int kb)->f16x8 {
    const float* p = x + (bs + m*16 + ln)*480 + t*60 + kb*32 + qd*8;
    f16x8 a;
    f32x4 lo = *(const f32x4*)p;
    #pragma unroll
    for (int i=0;i<4;i++) a[i] = (f16)lo[i];
    if (kb==1 && qd==3){
      #pragma unroll
      for (int i=0;i<4;i++) a[4+i] = (f16)0.f;
    } else {
      f32x4 hi = *(const f32x4*)(p+4);
      #pragma unroll
      for (int i=0;i<4;i++) a[4+i] = (f16)hi[i];
    }
    return a;
  };

  // ===================== P1: encoder layer 0 (K = 64(x,pad) + 128(h0)) ====
  #pragma unroll
  for (int g=0;g<4;g++){
    const int n = g*128 + col;
    #pragma unroll
    for (int kb=0;kb<2;kb++) Bf[g][kb]   = ldfrag60(e0Wih, n, kb*32 + qd*8);
    #pragma unroll
    for (int kb=0;kb<4;kb++) Bf[g][kb+2] = ldfrag(e0Whh, 128, n, kb*32 + qd*8);
    bg[g] = e0bi[n] + e0bh[n];
  }
  cst[0] = splat4(0.f); cst[1] = splat4(0.f);
  // prologue: accN = bias + Wih*x_0
  #pragma unroll
  for (int m=0;m<2;m++)
    #pragma unroll
    for (int g=0;g<4;g++) accN[m][g] = splat4(bg[g]);
  #pragma unroll
  for (int kb=0; kb<2; kb++)
    #pragma unroll
    for (int m=0;m<2;m++){
      f16x8 a = xfrag(m, 0, kb);
      #pragma unroll
      for (int g=0; g<4; g++) accN[m][g] = MFMA16(a, Bf[g][kb], accN[m][g]);
    }
  #pragma unroll
  for (int t=0; t<8; t++){
    #pragma unroll
    for (int m=0;m<2;m++)
      #pragma unroll
      for (int g=0;g<4;g++) acc[m][g] = accN[m][g];
    if (t > 0){                        // recurrent: h0_{t-1}
      #pragma unroll
      for (int kb=0; kb<4; kb++)
        #pragma unroll
        for (int m=0;m<2;m++){
          f16x8 a = *(const f16x8*)(hist + (m*16+ln)*HIST_S + (t-1)*HB_S + kb*32 + qd*8);
          #pragma unroll
          for (int g=0; g<4; g++) acc[m][g] = MFMA16(a, Bf[g][kb+2], acc[m][g]);
        }
    }
    if (t < 7){                        // inject: accN = bias + Wih*x_{t+1} (independent)
      #pragma unroll
      for (int m=0;m<2;m++)
        #pragma unroll
        for (int g=0;g<4;g++) accN[m][g] = splat4(bg[g]);
      #pragma unroll
      for (int kb=0; kb<2; kb++)
        #pragma unroll
        for (int m=0;m<2;m++){
          f16x8 a = xfrag(m, t+1, kb);
          #pragma unroll
          for (int g=0; g<4; g++) accN[m][g] = MFMA16(a, Bf[g][kb], accN[m][g]);
        }
    }
    act_update(acc, cst, hist + t*HB_S, HIST_S, col, qd);
    __syncthreads();
  }

  // ===================== P2: encoder layer 1 (K = 128(h0_t) + 128(h1)) ====
  #pragma unroll
  for (int g=0;g<4;g++){
    const int n = g*128 + col;
    #pragma unroll
    for (int kb=0;kb<4;kb++){
      Bf[g][kb]   = ldfrag(e1Wih, 128, n, kb*32 + qd*8);
      Bf[g][kb+4] = ldfrag(e1Whh, 128, n, kb*32 + qd*8);
    }
    bg[g] = e1bi[n] + e1bh[n];
  }
  cst[0] = splat4(0.f); cst[1] = splat4(0.f);
  // prologue: accN = bias + Wih*h0_0
  #pragma unroll
  for (int m=0;m<2;m++)
    #pragma unroll
    for (int g=0;g<4;g++) accN[m][g] = splat4(bg[g]);
  #pragma unroll
  for (int kb=0; kb<4; kb++)
    #pragma unroll
    for (int m=0;m<2;m++){
      f16x8 a = *(const f16x8*)(hist + (m*16+ln)*HIST_S + 0*HB_S + kb*32 + qd*8);
      #pragma unroll
      for (int g=0; g<4; g++) accN[m][g] = MFMA16(a, Bf[g][kb], accN[m][g]);
    }
  #pragma unroll
  for (int t=0; t<8; t++){
    #pragma unroll
    for (int m=0;m<2;m++)
      #pragma unroll
      for (int g=0;g<4;g++) acc[m][g] = accN[m][g];
    if (t > 0){                        // recurrent: h1_{t-1} from other ring buffer
      const f16* hb = hb1 + ((t-1)&1)*HB_BUF;
      #pragma unroll
      for (int kb=0; kb<4; kb++)
        #pragma unroll
        for (int m=0;m<2;m++){
          f16x8 a = *(const f16x8*)(hb + (m*16+ln)*HB_S + kb*32 + qd*8);
          #pragma unroll
          for (int g=0; g<4; g++) acc[m][g] = MFMA16(a, Bf[g][kb+4], acc[m][g]);
        }
    }
    if (t < 7){                        // inject: accN = bias + Wih*h0_{t+1} (hist read-only here)
      #pragma unroll
      for (int m=0;m<2;m++)
        #pragma unroll
        for (int g=0;g<4;g++) accN[m][g] = splat4(bg[g]);
      #pragma unroll
      for (int kb=0; kb<4; kb++)
        #pragma unroll
        for (int m=0;m<2;m++){
          f16x8 a = *(const f16x8*)(hist + (m*16+ln)*HIST_S + (t+1)*HB_S + kb*32 + qd*8);
          #pragma unroll
          for (int g=0; g<4; g++) accN[m][g] = MFMA16(a, Bf[g][kb], accN[m][g]);
        }
    }
    act_update(acc, cst, hb1 + (t&1)*HB_BUF, HB_S, col, qd);  // write buf t&1, read was (t-1)&1
    __syncthreads();
  }

  // ===================== P3: z = h1_7 @ Wlat^T + blat -> hb1 buf0 ==========
  {
    const int mo = w & 1, no = w >> 1;    // 2 m-tiles x 4 n-tiles across 8 waves
    const int zn = no*16 + ln;            // latent index 0..63
    f32x4 zacc = splat4(blat[zn]);
    f16x8 Bz[4];
    #pragma unroll
    for (int kb=0;kb<4;kb++) Bz[kb] = ldfrag(Wlat, 128, zn, kb*32 + qd*8);
    const f16* hb = hb1 + HB_BUF;         // h1_7 in buf1 (7&1)
    #pragma unroll
    for (int kb=0;kb<4;kb++){
      f16x8 a = *(const f16x8*)(hb + (mo*16+ln)*HB_S + kb*32 + qd*8);
      zacc = MFMA16(a, Bz[kb], zacc);
    }
    #pragma unroll
    for (int r=0;r<4;r++)
      hb1[(mo*16+qd*4+r)*HB_S + zn] = (f16)zacc[r];    // z -> buf0 (disjoint from buf1)
  }
  __syncthreads();

  // ===================== P4: decoder layer 0 (K = 64(z) + 128(d0)) ========
  // z is t-invariant: its 16 MFMAs are recomputed per t as injected shadow work
  #pragma unroll
  for (int g=0;g<4;g++){
    const int n = g*128 + col;
    #pragma unroll
    for (int kb=0;kb<2;kb++) Bf[g][kb]   = ldfrag(d0Wih, 64, n, kb*32 + qd*8);
    #pragma unroll
    for (int kb=0;kb<4;kb++) Bf[g][kb+2] = ldfrag(d0Whh, 128, n, kb*32 + qd*8);
    bg[g] = d0bi[n] + d0bh[n];
  }
  cst[0] = splat4(0.f); cst[1] = splat4(0.f);
  // prologue: accN = bias + Wih*z
  #pragma unroll
  for (int m=0;m<2;m++)
    #pragma unroll
    for (int g=0;g<4;g++) accN[m][g] = splat4(bg[g]);
  #pragma unroll
  for (int kb=0; kb<2; kb++)
    #pragma unroll
    for (int m=0;m<2;m++){
      f16x8 a = *(const f16x8*)(hb1 + (m*16+ln)*HB_S + kb*32 + qd*8);  // z (buf0)
      #pragma unroll
      for (int g=0; g<4; g++) accN[m][g] = MFMA16(a, Bf[g][kb], accN[m][g]);
    }
  #pragma unroll
  for (int t=0; t<8; t++){
    #pragma unroll
    for (int m=0;m<2;m++)
      #pragma unroll
      for (int g=0;g<4;g++) acc[m][g] = accN[m][g];
    if (t > 0){                        // recurrent: d0_{t-1}
      #pragma unroll
      for (int kb=0; kb<4; kb++)
        #pragma unroll
        for (int m=0;m<2;m++){
          f16x8 a = *(const f16x8*)(hist + (m*16+ln)*HIST_S + (t-1)*HB_S + kb*32 + qd*8);
          #pragma unroll
          for (int g=0; g<4; g++) acc[m][g] = MFMA16(a, Bf[g][kb+2], acc[m][g]);
        }
    }
    if (t < 7){                        // inject: accN = bias + Wih*z (z still in buf0)
      #pragma unroll
      for (int m=0;m<2;m++)
        #pragma unroll
        for (int g=0;g<4;g++) accN[m][g] = splat4(bg[g]);
      #pragma unroll
      for (int kb=0; kb<2; kb++)
        #pragma unroll
        for (int m=0;m<2;m++){
          f16x8 a = *(const f16x8*)(hb1 + (m*16+ln)*HB_S + kb*32 + qd*8);
          #pragma unroll
          for (int g=0; g<4; g++) accN[m][g] = MFMA16(a, Bf[g][kb], accN[m][g]);
        }
    }
    act_update(acc, cst, hist + t*HB_S, HIST_S, col, qd);  // d0 history overwrites enc history
    __syncthreads();
  }

  // ===================== P5: decoder layer 1 + output projection ==========
  #pragma unroll
  for (int g=0;g<4;g++){
    const int n = g*128 + col;
    #pragma unroll
    for (int kb=0;kb<4;kb++){
      Bf[g][kb]   = ldfrag(d1Wih, 128, n, kb*32 + qd*8);
      Bf[g][kb+4] = ldfrag(d1Whh, 128, n, kb*32 + qd*8);
    }
    bg[g] = d1bi[n] + d1bh[n];
  }
  const int dcol = (w>>1)*16 + ln;   // output feature index 0..63
  const int mo   = w & 1;            // out-proj m-tile for this wave
  f16x8 BO[4];
  #pragma unroll
  for (int kb=0;kb<4;kb++)
    BO[kb] = (dcol < 60) ? ldfrag(Wout, 128, dcol, kb*32 + qd*8) : zfrag();
  const float bo = (dcol < 60) ? bout[dcol] : 0.f;
  cst[0] = splat4(0.f); cst[1] = splat4(0.f);
  // prologue: accN = bias + Wih*d0_0
  #pragma unroll
  for (int m=0;m<2;m++)
    #pragma unroll
    for (int g=0;g<4;g++) accN[m][g] = splat4(bg[g]);
  #pragma unroll
  for (int kb=0; kb<4; kb++)
    #pragma unroll
    for (int m=0;m<2;m++){
      f16x8 a = *(const f16x8*)(hist + (m*16+ln)*HIST_S + 0*HB_S + kb*32 + qd*8);
      #pragma unroll
      for (int g=0; g<4; g++) accN[m][g] = MFMA16(a, Bf[g][kb], accN[m][g]);
    }
  #pragma unroll
  for (int t=0; t<8; t++){
    #pragma unroll
    for (int m=0;m<2;m++)
      #pragma unroll
      for (int g=0;g<4;g++) acc[m][g] = accN[m][g];
    if (t > 0){                        // recurrent: h_d1_{t-1} from other ring buffer
      const f16* hb = hb1 + ((t-1)&1)*HB_BUF;
      #pragma unroll
      for (int kb=0; kb<4; kb++)
        #pragma unroll
        for (int m=0;m<2;m++){
          f16x8 a = *(const f16x8*)(hb + (m*16+ln)*HB_S + kb*32 + qd*8);
          #pragma unroll
          for (int g=0; g<4; g++) acc[m][g] = MFMA16(a, Bf[g][kb+4], acc[m][g]);
        }
    }
    if (t < 7){                        // inject: accN = bias + Wih*d0_{t+1} (hist read-only here)
      #pragma unroll
      for (int m=0;m<2;m++)
        #pragma unroll
        for (int g=0;g<4;g++) accN[m][g] = splat4(bg[g]);
      #pragma unroll
      for (int kb=0; kb<4; kb++)
        #pragma unroll
        for (int m=0;m<2;m++){
          f16x8 a = *(const f16x8*)(hist + (m*16+ln)*HIST_S + (t+1)*HB_S + kb*32 + qd*8);
          #pragma unroll
          for (int g=0; g<4; g++) accN[m][g] = MFMA16(a, Bf[g][kb], accN[m][g]);
        }
    }
    act_update(acc, cst, hb1 + (t&1)*HB_BUF, HB_S, col, qd);
    __syncthreads();                   // h_d1_t visible
    // ---- out_t = h_d1_t @ W_out^T + b_out (each wave: 1 m-tile x 1 n-tile)
    // safe: next write to buf t&1 is at t+2, after barrier(t+1), which every
    // wave reaches only after finishing this read.
    f32x4 ao = splat4(bo);
    const f16* hb2 = hb1 + (t&1)*HB_BUF + (mo*16+ln)*HB_S + qd*8;
    #pragma unroll
    for (int kb=0; kb<4; kb++){
      f16x8 a = *(const f16x8*)(hb2 + kb*32);
      ao = MFMA16(a, BO[kb], ao);
    }
    if (dcol < 60){
      #pragma unroll
      for (int r=0;r<4;r++){
        int s = mo*16 + qd*4 + r;
        out[(bs + s)*480 + t*60 + dcol] = ao[r];
      }
    }
  }
}

// ---------------- host launch ---------------------------------------------
extern "C" void kernel_launch(void* const* d_in, const int* in_sizes, int n_in,
                              void* d_out, int out_size, void* d_ws, size_t ws_size,
                              hipStream_t stream)
{
  (void)d_ws; (void)ws_size; (void)in_sizes; (void)n_in; (void)out_size;
  hipLaunchKernelGGL(lstm_main, dim3(2048), dim3(512), 0, stream,
                     (const float*)d_in[0],
                     (const float*)d_in[1],  (const float*)d_in[2],  (const float*)d_in[3],  (const float*)d_in[4],
                     (const float*)d_in[5],  (const float*)d_in[6],  (const float*)d_in[7],  (const float*)d_in[8],
                     (const float*)d_in[9],  (const float*)d_in[10], (const float*)d_in[11], (const float*)d_in[12],
                     (const float*)d_in[13], (const float*)d_in[14], (const float*)d_in[15], (const float*)d_in[16],
                     (const float*)d_in[17], (const float*)d_in[18],
                     (const float*)d_in[19], (const float*)d_in[20],
                     (float*)d_out);
}